// Round 5
// baseline (429.463 us; speedup 1.0000x reference)
//
#include <hip/hip_runtime.h>
#include <stdint.h>

// Problem: DynamicVoxelizer. B=8, N=1e6, voxel=0.2, grid (x,y,z)=(512,512,30).
// d_out = FLOAT32 x 88,000,000, concatenated:
//   [0,   24M)  out_points    (B,N,3)
//   [24M, 48M)  coords_zyx    (B,N,3)
//   [48M, 56M)  point_idxes   (B,N)
//   [56M, 80M)  point_offsets (B,N,3)
//   [80M, 88M)  valid         (B,N)
// d_in[0] = FLOAT32 x 24,000,000 (B,N,3).
// R3 passed at ~200us kernel vs 71us roofline (448 MB @ 6.3 TB/s).
// R4 failed to compile: __builtin_nontemporal_* rejects HIP_vector_type.
// R5: same nt-store plan via clang native ext_vector_type(4) float.

#define NPB   1000000
#define TOT   8000000
#define PPT   4                 // points per thread; 4 | NPB so no batch straddle
#define NTHR  (TOT / PPT)       // 2,000,000 threads

typedef float fx4 __attribute__((ext_vector_type(4)));

__global__ __launch_bounds__(256) void voxelize_kernel(
        const float* __restrict__ pts, float* __restrict__ out) {
    int t = blockIdx.x * 256 + threadIdx.x;
    if (t >= NTHR) return;
    int g0 = t * PPT;            // first global point index
    int b  = g0 / NPB;
    int n0 = g0 - b * NPB;       // index within batch

    // ---- load 4 points = 12 floats = 3 x 16B (t*48B -> 16B aligned) ----
    union { fx4 v4[3]; float f[12]; } in;      // union punning: OK in clang
    const fx4* src = (const fx4*)(pts + (size_t)g0 * 3);
#pragma unroll
    for (int i = 0; i < 3; ++i) in.v4[i] = __builtin_nontemporal_load(src + i);

    float opb[12], cob[12], ofb[12], idb[4], vab[4];

#pragma unroll
    for (int j = 0; j < PPT; ++j) {
        float x = in.f[3*j], y = in.f[3*j+1], z = in.f[3*j+2];
        bool nn = (x == x) && (y == y) && (z == z);        // !any(isnan)
        float px = nn ? x : 0.0f;
        float py = nn ? y : 0.0f;
        float pz = nn ? z : 0.0f;
        // Exact numpy fp32 sequence: (p - min)/vs, floor, int cast.
        // Division by 0.2f must stay a division (x*5.0f differs near voxel
        // boundaries; O(100) coord flips over 24M values would blow absmax).
        float tx = (px + 51.2f) / 0.2f;
        float ty = (py + 51.2f) / 0.2f;
        float tz = (pz + 3.0f)  / 0.2f;
        int cx = (int)floorf(tx);
        int cy = (int)floorf(ty);
        int cz = (int)floorf(tz);
        bool valid = nn && (cx >= 0) && (cx < 512)
                        && (cy >= 0) && (cy < 512)
                        && (cz >= 0) && (cz < 30);
        float ctx = ((float)cx * 0.2f + (-51.2f)) + 0.1f;
        float cty = ((float)cy * 0.2f + (-51.2f)) + 0.1f;
        float ctz = ((float)cz * 0.2f + (-3.0f))  + 0.1f;

        opb[3*j+0] = valid ? px : 0.0f;
        opb[3*j+1] = valid ? py : 0.0f;
        opb[3*j+2] = valid ? pz : 0.0f;

        cob[3*j+0] = valid ? (float)cz : -1.0f;   // zyx order
        cob[3*j+1] = valid ? (float)cy : -1.0f;
        cob[3*j+2] = valid ? (float)cx : -1.0f;

        ofb[3*j+0] = valid ? (px - ctx) : 0.0f;
        ofb[3*j+1] = valid ? (py - cty) : 0.0f;
        ofb[3*j+2] = valid ? (pz - ctz) : 0.0f;

        idb[j] = valid ? (float)(n0 + j) : -1.0f;
        vab[j] = valid ? 1.0f : 0.0f;
    }

    // ---- stores: 11 x 16B, 16B-aligned, nontemporal (stream past L2) ----
    size_t p3 = (size_t)g0 * 3;          // 12 floats per thread -> 48B stride
    fx4* dp0 = (fx4*)(out + p3);
    fx4* dp1 = (fx4*)(out + (size_t)24000000 + p3);
    fx4* dp3 = (fx4*)(out + (size_t)56000000 + p3);
#pragma unroll
    for (int q = 0; q < 3; ++q) {
        fx4 v = { opb[4*q], opb[4*q+1], opb[4*q+2], opb[4*q+3] };
        __builtin_nontemporal_store(v, dp0 + q);
    }
#pragma unroll
    for (int q = 0; q < 3; ++q) {
        fx4 v = { cob[4*q], cob[4*q+1], cob[4*q+2], cob[4*q+3] };
        __builtin_nontemporal_store(v, dp1 + q);
    }
    {
        fx4 v = { idb[0], idb[1], idb[2], idb[3] };
        __builtin_nontemporal_store(v, (fx4*)(out + (size_t)48000000 + (size_t)g0));
    }
#pragma unroll
    for (int q = 0; q < 3; ++q) {
        fx4 v = { ofb[4*q], ofb[4*q+1], ofb[4*q+2], ofb[4*q+3] };
        __builtin_nontemporal_store(v, dp3 + q);
    }
    {
        fx4 v = { vab[0], vab[1], vab[2], vab[3] };
        __builtin_nontemporal_store(v, (fx4*)(out + (size_t)80000000 + (size_t)g0));
    }
}

extern "C" void kernel_launch(void* const* d_in, const int* in_sizes, int n_in,
                              void* d_out, int out_size, void* d_ws, size_t ws_size,
                              hipStream_t stream) {
    const float* pts = (const float*)d_in[0];
    float* out = (float*)d_out;
    int blocks = (NTHR + 255) / 256;   // 7813
    voxelize_kernel<<<blocks, 256, 0, stream>>>(pts, out);
}

// Round 6
// 407.332 us; speedup vs baseline: 1.0543x; 1.0543x over previous
//
#include <hip/hip_runtime.h>
#include <stdint.h>

// Problem: DynamicVoxelizer. B=8, N=1e6, voxel=0.2, grid (x,y,z)=(512,512,30).
// d_out = FLOAT32 x 88,000,000, concatenated:
//   [0,   24M)  out_points(B,N,3)  [24M,48M) coords_zyx  [48M,56M) idx
//   [56M, 80M)  point_offsets      [80M,88M) valid
// History: R3 passed, kernel ~123us (dur 424 = ~306us harness fills + kernel)
// vs 71us roofline. R5 nt-stores neutral -> L2-churn theory dead. R6 theory:
// partial-line stores (48B lane stride) cost read-for-ownership (~352MB hidden
// fetch). Fix: LDS-stage vec3 regions so every store instruction is
// lane-contiguous 16B/lane = full-line coverage (like the 6.4TB/s fill kernels).

#define NPB   1000000
#define TOT   8000000
#define PPT   4
#define BLK   256
#define PPB   (BLK * PPT)                 // 1024 points per block
#define NBLK  ((TOT + PPB - 1) / PPB)     // 7813 (last block half-full)

typedef float fx4 __attribute__((ext_vector_type(4)));

__global__ __launch_bounds__(256) void voxelize_kernel(
        const float* __restrict__ pts, float* __restrict__ out) {
    __shared__ fx4 lsA[PPB * 3 / 4];   // out_points   12 KB
    __shared__ fx4 lsB[PPB * 3 / 4];   // coords_zyx   12 KB
    __shared__ fx4 lsC[PPB * 3 / 4];   // offsets      12 KB

    int t  = threadIdx.x;
    int p0 = blockIdx.x * PPB + t * PPT;   // first point for this thread

    if (p0 < TOT) {                        // all-or-nothing: 4 | p0, 4 | TOT
        int b  = p0 / NPB;                 // 4 | NPB -> no batch straddle in-thread
        int n0 = p0 - b * NPB;

        union { fx4 v4[3]; float f[12]; } in;
        const fx4* src = (const fx4*)(pts + (size_t)p0 * 3);
#pragma unroll
        for (int i = 0; i < 3; ++i) in.v4[i] = __builtin_nontemporal_load(src + i);

        float opb[12], cob[12], ofb[12], idb[4], vab[4];
#pragma unroll
        for (int j = 0; j < PPT; ++j) {
            float x = in.f[3*j], y = in.f[3*j+1], z = in.f[3*j+2];
            bool nn = (x == x) && (y == y) && (z == z);
            float px = nn ? x : 0.0f;
            float py = nn ? y : 0.0f;
            float pz = nn ? z : 0.0f;
            // Exact numpy fp32 sequence: (p - min)/vs, floor, int cast.
            // Division must stay a division (x*5.0f flips voxel boundaries).
            float tx = (px + 51.2f) / 0.2f;
            float ty = (py + 51.2f) / 0.2f;
            float tz = (pz + 3.0f)  / 0.2f;
            int cx = (int)floorf(tx);
            int cy = (int)floorf(ty);
            int cz = (int)floorf(tz);
            bool valid = nn && (cx >= 0) && (cx < 512)
                            && (cy >= 0) && (cy < 512)
                            && (cz >= 0) && (cz < 30);
            float ctx = ((float)cx * 0.2f + (-51.2f)) + 0.1f;
            float cty = ((float)cy * 0.2f + (-51.2f)) + 0.1f;
            float ctz = ((float)cz * 0.2f + (-3.0f))  + 0.1f;

            opb[3*j+0] = valid ? px : 0.0f;
            opb[3*j+1] = valid ? py : 0.0f;
            opb[3*j+2] = valid ? pz : 0.0f;
            cob[3*j+0] = valid ? (float)cz : -1.0f;
            cob[3*j+1] = valid ? (float)cy : -1.0f;
            cob[3*j+2] = valid ? (float)cx : -1.0f;
            ofb[3*j+0] = valid ? (px - ctx) : 0.0f;
            ofb[3*j+1] = valid ? (py - cty) : 0.0f;
            ofb[3*j+2] = valid ? (pz - ctz) : 0.0f;
            idb[j] = valid ? (float)(n0 + j) : -1.0f;
            vab[j] = valid ? 1.0f : 0.0f;
        }

        // Stage vec3 regions to LDS in output layout (fx4 index = point-float/4).
#pragma unroll
        for (int q = 0; q < 3; ++q) {
            fx4 a = { opb[4*q], opb[4*q+1], opb[4*q+2], opb[4*q+3] };
            fx4 c = { cob[4*q], cob[4*q+1], cob[4*q+2], cob[4*q+3] };
            fx4 o = { ofb[4*q], ofb[4*q+1], ofb[4*q+2], ofb[4*q+3] };
            lsA[t*3 + q] = a;
            lsB[t*3 + q] = c;
            lsC[t*3 + q] = o;
        }

        // Scalar regions: already lane-contiguous (16B/lane) -> direct store.
        {
            fx4 v = { idb[0], idb[1], idb[2], idb[3] };
            *(fx4*)(out + (size_t)48000000 + (size_t)p0) = v;
        }
        {
            fx4 v = { vab[0], vab[1], vab[2], vab[3] };
            *(fx4*)(out + (size_t)80000000 + (size_t)p0) = v;
        }
    }

    __syncthreads();

    // Cooperative lane-contiguous stores: 768 fx4 per region per block.
    // Instruction i: lane t stores fx4 #(i*256+t) -> 16B lane stride, 1KB/wave.
    size_t f40 = (size_t)blockIdx.x * (PPB * 3 / 4);   // block's first fx4 in region
#pragma unroll
    for (int i = 0; i < 3; ++i) {
        int    li  = i * BLK + t;          // fx4 index within block
        size_t f4i = f40 + li;
        if (f4i < (size_t)6000000) {       // 24M floats = 6M fx4 per region
            ((fx4*)(out))[f4i]                               = lsA[li];
            ((fx4*)(out + (size_t)24000000))[f4i]            = lsB[li];
            ((fx4*)(out + (size_t)56000000))[f4i]            = lsC[li];
        }
    }
}

extern "C" void kernel_launch(void* const* d_in, const int* in_sizes, int n_in,
                              void* d_out, int out_size, void* d_ws, size_t ws_size,
                              hipStream_t stream) {
    const float* pts = (const float*)d_in[0];
    float* out = (float*)d_out;
    voxelize_kernel<<<NBLK, BLK, 0, stream>>>(pts, out);
}

// Round 7
// 405.466 us; speedup vs baseline: 1.0592x; 1.0046x over previous
//
#include <hip/hip_runtime.h>
#include <stdint.h>

// Problem: DynamicVoxelizer. B=8, N=1e6, voxel=0.2, grid (x,y,z)=(512,512,30).
// d_out = FLOAT32 x 88,000,000, concatenated:
//   [0,24M) out_points  [24M,48M) coords_zyx  [48M,56M) idx
//   [56M,80M) offsets   [80M,88M) valid
// History: R3 424us, R5 nt neutral, R6 LDS-staged vec3 stores 407us.
// Timed window = ~309us harness fills/restore + kernel (~98us in R6).
// R7: strided point mapping (thread t -> points t+j*256) so ALL accesses are
// lane-contiguous: input 12B/lane, LDS writes 12B/lane (conflict-free),
// idx/valid 4B/lane dwords, cooperative fx4 stores unchanged. nt dropped.

#define NPB   1000000
#define TOT   8000000
#define BLK   256
#define PPT   4
#define PPB   (BLK * PPT)                 // 1024 points per block
#define NBLK  ((TOT + PPB - 1) / PPB)     // 7813 (last block partial)

typedef float fx4 __attribute__((ext_vector_type(4)));

__global__ __launch_bounds__(256) void voxelize_kernel(
        const float* __restrict__ pts, float* __restrict__ out) {
    __shared__ float lsA[PPB * 3];   // out_points   12 KB
    __shared__ float lsB[PPB * 3];   // coords_zyx   12 KB
    __shared__ float lsC[PPB * 3];   // offsets      12 KB

    int t = threadIdx.x;
    uint32_t P0 = (uint32_t)blockIdx.x * PPB;

#pragma unroll
    for (int j = 0; j < PPT; ++j) {
        int      pb = j * BLK + t;       // point index within block
        uint32_t n  = P0 + pb;           // global point index
        if (n < TOT) {
            uint32_t b  = n / NPB;       // magic-mul
            uint32_t ni = n - b * NPB;   // index within batch

            // 12B/lane contiguous load (compiler merges to dwordx3)
            const float* pp = pts + (size_t)n * 3;
            float x = pp[0], y = pp[1], z = pp[2];

            bool nn = (x == x) && (y == y) && (z == z);
            float px = nn ? x : 0.0f;
            float py = nn ? y : 0.0f;
            float pz = nn ? z : 0.0f;
            // Exact numpy fp32 sequence: (p - min)/vs, floor, int cast.
            // Division must stay a division (x*5.0f flips voxel boundaries).
            float tx = (px + 51.2f) / 0.2f;
            float ty = (py + 51.2f) / 0.2f;
            float tz = (pz + 3.0f)  / 0.2f;
            int cx = (int)floorf(tx);
            int cy = (int)floorf(ty);
            int cz = (int)floorf(tz);
            bool valid = nn && (cx >= 0) && (cx < 512)
                            && (cy >= 0) && (cy < 512)
                            && (cz >= 0) && (cz < 30);
            float ctx = ((float)cx * 0.2f + (-51.2f)) + 0.1f;
            float cty = ((float)cy * 0.2f + (-51.2f)) + 0.1f;
            float ctz = ((float)cz * 0.2f + (-3.0f))  + 0.1f;

            // LDS staging: 12B/lane contiguous, conflict-free (3t mod 32 distinct)
            lsA[3*pb+0] = valid ? px : 0.0f;
            lsA[3*pb+1] = valid ? py : 0.0f;
            lsA[3*pb+2] = valid ? pz : 0.0f;
            lsB[3*pb+0] = valid ? (float)cz : -1.0f;   // zyx order
            lsB[3*pb+1] = valid ? (float)cy : -1.0f;
            lsB[3*pb+2] = valid ? (float)cx : -1.0f;
            lsC[3*pb+0] = valid ? (px - ctx) : 0.0f;
            lsC[3*pb+1] = valid ? (py - cty) : 0.0f;
            lsC[3*pb+2] = valid ? (pz - ctz) : 0.0f;

            // Scalar regions: 4B/lane contiguous dword stores
            out[(size_t)48000000 + n] = valid ? (float)ni : -1.0f;
            out[(size_t)80000000 + n] = valid ? 1.0f : 0.0f;
        }
    }

    __syncthreads();

    // Cooperative lane-contiguous stores: 768 fx4 per region per block.
    size_t f40 = (size_t)blockIdx.x * (PPB * 3 / 4);
#pragma unroll
    for (int i = 0; i < 3; ++i) {
        int    li  = i * BLK + t;          // fx4 index within block
        size_t f4i = f40 + li;
        if (f4i < (size_t)6000000) {       // 24M floats = 6M fx4 per region
            fx4 a = ((const fx4*)lsA)[li];
            fx4 c = ((const fx4*)lsB)[li];
            fx4 o = ((const fx4*)lsC)[li];
            ((fx4*)(out))[f4i]                    = a;
            ((fx4*)(out + (size_t)24000000))[f4i] = c;
            ((fx4*)(out + (size_t)56000000))[f4i] = o;
        }
    }
}

extern "C" void kernel_launch(void* const* d_in, const int* in_sizes, int n_in,
                              void* d_out, int out_size, void* d_ws, size_t ws_size,
                              hipStream_t stream) {
    const float* pts = (const float*)d_in[0];
    float* out = (float*)d_out;
    voxelize_kernel<<<NBLK, BLK, 0, stream>>>(pts, out);
}